// Round 1
// baseline (615.129 us; speedup 1.0000x reference)
//
#include <hip/hip_runtime.h>

#define E 512
#define Hh 8
#define Dd 64
#define Ss 4096
#define Bb 2

typedef _Float16 f16;
typedef __attribute__((ext_vector_type(8))) _Float16 f16x8;
typedef __attribute__((ext_vector_type(4))) float f32x4;

// ---------------- convert emb fp32 -> f16 ----------------
__global__ __launch_bounds__(256) void cvt_emb_kernel(const float* __restrict__ in,
                                                      f16* __restrict__ out) {
    int i = (blockIdx.x * 256 + threadIdx.x) * 8;
    float4 a = *(const float4*)(in + i);
    float4 b = *(const float4*)(in + i + 4);
    f16x8 o;
    o[0] = (f16)a.x; o[1] = (f16)a.y; o[2] = (f16)a.z; o[3] = (f16)a.w;
    o[4] = (f16)b.x; o[5] = (f16)b.y; o[6] = (f16)b.z; o[7] = (f16)b.w;
    *(f16x8*)(out + i) = o;
}

// ------------- transpose weights -> Wt[n][k] f16 -------------
// n in [0,1536) -> wq/wk/wv into wtqkv ; n in [1536,2048) -> wo into wto
__global__ __launch_bounds__(64) void cvt_w_kernel(const float* __restrict__ wq,
                                                   const float* __restrict__ wk,
                                                   const float* __restrict__ wv,
                                                   const float* __restrict__ wo,
                                                   f16* __restrict__ wtqkv,
                                                   f16* __restrict__ wto) {
    int n = blockIdx.x;      // 0..2047
    int t = threadIdx.x;     // 0..63
    const float* src;
    f16* dst;
    int col = n & 511;
    if (n < 1536) {
        int which = n >> 9;
        src = (which == 0) ? wq : (which == 1) ? wk : wv;
        dst = wtqkv + (size_t)n * E;
    } else {
        src = wo;
        dst = wto + (size_t)(n - 1536) * E;
    }
    int k0 = t * 8;
    f16x8 o;
#pragma unroll
    for (int j = 0; j < 8; ++j) o[j] = (f16)src[(size_t)(k0 + j) * E + col];
    *(f16x8*)(dst + k0) = o;
}

// ---------------- QKV projection GEMM ----------------
// C[m][n] = sum_k A[m][k] * Wt[n][k],  M=8192, N=1536, K=512
// epilogue: +bias, scatter Q(scaled 1/8)->[B,H,S,D], K->[B,H,S,D], V->[B,H,D,S]
#define LDP 40  // padded LDS row stride (f16 elems); 80B => bank stride 20 => <=2-way

__global__ __launch_bounds__(256) void gemm_qkv_kernel(
    const f16* __restrict__ A, const f16* __restrict__ Wt,
    const float* __restrict__ bq, const float* __restrict__ bk,
    const float* __restrict__ bv,
    f16* __restrict__ Qb, f16* __restrict__ Kb, f16* __restrict__ Vt) {
    __shared__ f16 As[128 * LDP];
    __shared__ f16 Bs[128 * LDP];
    int tid = threadIdx.x;
    int m0 = blockIdx.x * 128, n0 = blockIdx.y * 128;
    int w = tid >> 6, lane = tid & 63;
    int wr = w >> 1, wc = w & 1;
    int lgrp = lane >> 4, l16 = lane & 15;
    f32x4 acc[4][4];
#pragma unroll
    for (int i = 0; i < 4; ++i)
#pragma unroll
        for (int j = 0; j < 4; ++j) acc[i][j] = (f32x4){0.f, 0.f, 0.f, 0.f};

    for (int kt = 0; kt < 16; ++kt) {
        int k0 = kt * 32;
        {
            int c = tid, row = c >> 2, seg = c & 3;
            *(f16x8*)&As[row * LDP + seg * 8] = *(const f16x8*)&A[(size_t)(m0 + row) * E + k0 + seg * 8];
            *(f16x8*)&Bs[row * LDP + seg * 8] = *(const f16x8*)&Wt[(size_t)(n0 + row) * E + k0 + seg * 8];
            c = tid + 256; row = c >> 2; seg = c & 3;
            *(f16x8*)&As[row * LDP + seg * 8] = *(const f16x8*)&A[(size_t)(m0 + row) * E + k0 + seg * 8];
            *(f16x8*)&Bs[row * LDP + seg * 8] = *(const f16x8*)&Wt[(size_t)(n0 + row) * E + k0 + seg * 8];
        }
        __syncthreads();
        f16x8 af[4], bfr[4];
#pragma unroll
        for (int mi = 0; mi < 4; ++mi)
            af[mi] = *(const f16x8*)&As[(wr * 64 + mi * 16 + l16) * LDP + lgrp * 8];
#pragma unroll
        for (int ni = 0; ni < 4; ++ni)
            bfr[ni] = *(const f16x8*)&Bs[(wc * 64 + ni * 16 + l16) * LDP + lgrp * 8];
#pragma unroll
        for (int mi = 0; mi < 4; ++mi)
#pragma unroll
            for (int ni = 0; ni < 4; ++ni)
                acc[mi][ni] = __builtin_amdgcn_mfma_f32_16x16x32_f16(af[mi], bfr[ni], acc[mi][ni], 0, 0, 0);
        __syncthreads();
    }
    // epilogue: D row=(lane>>4)*4+r, col=lane&15  [m89-verified]
#pragma unroll
    for (int mi = 0; mi < 4; ++mi) {
#pragma unroll
        for (int ni = 0; ni < 4; ++ni) {
#pragma unroll
            for (int r = 0; r < 4; ++r) {
                int gm = m0 + wr * 64 + mi * 16 + lgrp * 4 + r;
                int gn = n0 + wc * 64 + ni * 16 + l16;
                int which = gn >> 9, e = gn & 511;
                int h = e >> 6, d = e & 63;
                int b = gm >> 12, s = gm & 4095;
                float v = acc[mi][ni][r];
                if (which == 0) {
                    v = (v + bq[e]) * 0.125f;  // fold 1/sqrt(64) into Q
                    Qb[(size_t)((b * Hh + h) * Ss + s) * Dd + d] = (f16)v;
                } else if (which == 1) {
                    v += bk[e];
                    Kb[(size_t)((b * Hh + h) * Ss + s) * Dd + d] = (f16)v;
                } else {
                    v += bv[e];
                    Vt[(size_t)((b * Hh + h) * Dd + d) * Ss + s] = (f16)v;
                }
            }
        }
    }
}

// ---------------- causal flash attention ----------------
// grid: (S/64, B*H), block 256 = 4 waves; wave handles 16 q rows, KV tiles of 32
__global__ __launch_bounds__(256) void attn_kernel(const f16* __restrict__ Qb,
                                                   const f16* __restrict__ Kb,
                                                   const f16* __restrict__ Vt,
                                                   f16* __restrict__ attn) {
    __shared__ f16 P[4][16 * LDP];
    int tid = threadIdx.x;
    int w = tid >> 6, lane = tid & 63;
    int lgrp = lane >> 4, l16 = lane & 15;
    int bh = blockIdx.y;
    int q0 = blockIdx.x * 64 + w * 16;
    const f16* Qp = Qb + (size_t)bh * Ss * Dd;
    const f16* Kp = Kb + (size_t)bh * Ss * Dd;
    const f16* Vp = Vt + (size_t)bh * Dd * Ss;

    f16x8 qf[2];
#pragma unroll
    for (int kb = 0; kb < 2; ++kb)
        qf[kb] = *(const f16x8*)&Qp[(size_t)(q0 + l16) * Dd + kb * 32 + lgrp * 8];

    f32x4 o[4];
#pragma unroll
    for (int ds = 0; ds < 4; ++ds) o[ds] = (f32x4){0.f, 0.f, 0.f, 0.f};
    float m_run[4], l_run[4];
#pragma unroll
    for (int r = 0; r < 4; ++r) { m_run[r] = -INFINITY; l_run[r] = 0.f; }

    int ntiles = (q0 + 47) >> 5;  // kv tiles with n0 <= q0+15
    for (int t = 0; t < ntiles; ++t) {
        int n0 = t * 32;
        f16x8 kf0[2], kf1[2];
#pragma unroll
        for (int kb = 0; kb < 2; ++kb) {
            kf0[kb] = *(const f16x8*)&Kp[(size_t)(n0 + l16) * Dd + kb * 32 + lgrp * 8];
            kf1[kb] = *(const f16x8*)&Kp[(size_t)(n0 + 16 + l16) * Dd + kb * 32 + lgrp * 8];
        }
        f32x4 sc0 = {0.f, 0.f, 0.f, 0.f}, sc1 = {0.f, 0.f, 0.f, 0.f};
#pragma unroll
        for (int kb = 0; kb < 2; ++kb) {
            sc0 = __builtin_amdgcn_mfma_f32_16x16x32_f16(qf[kb], kf0[kb], sc0, 0, 0, 0);
            sc1 = __builtin_amdgcn_mfma_f32_16x16x32_f16(qf[kb], kf1[kb], sc1, 0, 0, 0);
        }
        int kv0 = n0 + l16, kv1 = n0 + 16 + l16;
        float p0[4], p1[4], scl[4];
#pragma unroll
        for (int r = 0; r < 4; ++r) {
            int qrow = q0 + lgrp * 4 + r;
            float v0 = (kv0 > qrow) ? -INFINITY : sc0[r];
            float v1 = (kv1 > qrow) ? -INFINITY : sc1[r];
            float pm = fmaxf(v0, v1);
            pm = fmaxf(pm, __shfl_xor(pm, 1));
            pm = fmaxf(pm, __shfl_xor(pm, 2));
            pm = fmaxf(pm, __shfl_xor(pm, 4));
            pm = fmaxf(pm, __shfl_xor(pm, 8));
            float mn = fmaxf(m_run[r], pm);
            float sc_ = __expf(m_run[r] - mn);
            p0[r] = __expf(v0 - mn);
            p1[r] = __expf(v1 - mn);
            float ps = p0[r] + p1[r];
            ps += __shfl_xor(ps, 1);
            ps += __shfl_xor(ps, 2);
            ps += __shfl_xor(ps, 4);
            ps += __shfl_xor(ps, 8);
            l_run[r] = l_run[r] * sc_ + ps;
            m_run[r] = mn;
            scl[r] = sc_;
        }
#pragma unroll
        for (int ds = 0; ds < 4; ++ds)
#pragma unroll
            for (int r = 0; r < 4; ++r) o[ds][r] *= scl[r];
        // re-layout P (D-frag -> A-frag) through per-wave LDS
#pragma unroll
        for (int r = 0; r < 4; ++r) {
            P[w][(lgrp * 4 + r) * LDP + l16] = (f16)p0[r];
            P[w][(lgrp * 4 + r) * LDP + 16 + l16] = (f16)p1[r];
        }
        asm volatile("s_waitcnt lgkmcnt(0)" ::: "memory");
        f16x8 pa = *(const f16x8*)&P[w][l16 * LDP + lgrp * 8];
#pragma unroll
        for (int ds = 0; ds < 4; ++ds) {
            f16x8 vf = *(const f16x8*)&Vp[(size_t)(ds * 16 + l16) * Ss + n0 + lgrp * 8];
            o[ds] = __builtin_amdgcn_mfma_f32_16x16x32_f16(pa, vf, o[ds], 0, 0, 0);
        }
    }
    int b = bh >> 3, h = bh & 7;
#pragma unroll
    for (int r = 0; r < 4; ++r) {
        float inv = 1.f / l_run[r];
        int s = q0 + lgrp * 4 + r;
#pragma unroll
        for (int ds = 0; ds < 4; ++ds)
            attn[(size_t)(b * Ss + s) * E + h * 64 + ds * 16 + l16] = (f16)(o[ds][r] * inv);
    }
}

// ---------------- output projection + bias + residual ----------------
__global__ __launch_bounds__(256) void gemm_out_kernel(
    const f16* __restrict__ A, const f16* __restrict__ Wt,
    const float* __restrict__ bo, const float* __restrict__ emb,
    float* __restrict__ xout) {
    __shared__ f16 As[128 * LDP];
    __shared__ f16 Bs[128 * LDP];
    int tid = threadIdx.x;
    int m0 = blockIdx.x * 128, n0 = blockIdx.y * 128;
    int w = tid >> 6, lane = tid & 63;
    int wr = w >> 1, wc = w & 1;
    int lgrp = lane >> 4, l16 = lane & 15;
    f32x4 acc[4][4];
#pragma unroll
    for (int i = 0; i < 4; ++i)
#pragma unroll
        for (int j = 0; j < 4; ++j) acc[i][j] = (f32x4){0.f, 0.f, 0.f, 0.f};

    for (int kt = 0; kt < 16; ++kt) {
        int k0 = kt * 32;
        {
            int c = tid, row = c >> 2, seg = c & 3;
            *(f16x8*)&As[row * LDP + seg * 8] = *(const f16x8*)&A[(size_t)(m0 + row) * E + k0 + seg * 8];
            *(f16x8*)&Bs[row * LDP + seg * 8] = *(const f16x8*)&Wt[(size_t)(n0 + row) * E + k0 + seg * 8];
            c = tid + 256; row = c >> 2; seg = c & 3;
            *(f16x8*)&As[row * LDP + seg * 8] = *(const f16x8*)&A[(size_t)(m0 + row) * E + k0 + seg * 8];
            *(f16x8*)&Bs[row * LDP + seg * 8] = *(const f16x8*)&Wt[(size_t)(n0 + row) * E + k0 + seg * 8];
        }
        __syncthreads();
        f16x8 af[4], bfr[4];
#pragma unroll
        for (int mi = 0; mi < 4; ++mi)
            af[mi] = *(const f16x8*)&As[(wr * 64 + mi * 16 + l16) * LDP + lgrp * 8];
#pragma unroll
        for (int ni = 0; ni < 4; ++ni)
            bfr[ni] = *(const f16x8*)&Bs[(wc * 64 + ni * 16 + l16) * LDP + lgrp * 8];
#pragma unroll
        for (int mi = 0; mi < 4; ++mi)
#pragma unroll
            for (int ni = 0; ni < 4; ++ni)
                acc[mi][ni] = __builtin_amdgcn_mfma_f32_16x16x32_f16(af[mi], bfr[ni], acc[mi][ni], 0, 0, 0);
        __syncthreads();
    }
#pragma unroll
    for (int mi = 0; mi < 4; ++mi) {
#pragma unroll
        for (int ni = 0; ni < 4; ++ni) {
#pragma unroll
            for (int r = 0; r < 4; ++r) {
                int gm = m0 + wr * 64 + mi * 16 + lgrp * 4 + r;
                int gn = n0 + wc * 64 + ni * 16 + l16;
                size_t idx = (size_t)gm * E + gn;
                xout[idx] = acc[mi][ni][r] + bo[gn] + emb[idx];
            }
        }
    }
}

// ---------------- LayerNorm ----------------
// block 256 = 4 waves, 1 wave per row of 512
__global__ __launch_bounds__(256) void ln_kernel(const float* __restrict__ x,
                                                 const float* __restrict__ g,
                                                 const float* __restrict__ b,
                                                 float* __restrict__ out) {
    int w = threadIdx.x >> 6, lane = threadIdx.x & 63;
    int row = blockIdx.x * 4 + w;
    const float* xr = x + (size_t)row * E;
    int c0 = lane * 8;
    float4 a = *(const float4*)&xr[c0];
    float4 c = *(const float4*)&xr[c0 + 4];
    float s = a.x + a.y + a.z + a.w + c.x + c.y + c.z + c.w;
    float q = a.x * a.x + a.y * a.y + a.z * a.z + a.w * a.w +
              c.x * c.x + c.y * c.y + c.z * c.z + c.w * c.w;
#pragma unroll
    for (int m = 1; m <= 32; m <<= 1) {
        s += __shfl_xor(s, m);
        q += __shfl_xor(q, m);
    }
    float mean = s * (1.f / 512.f);
    float var = q * (1.f / 512.f) - mean * mean;
    float rstd = rsqrtf(var + 1e-5f);
    float4 o1, o2;
    o1.x = (a.x - mean) * rstd * g[c0 + 0] + b[c0 + 0];
    o1.y = (a.y - mean) * rstd * g[c0 + 1] + b[c0 + 1];
    o1.z = (a.z - mean) * rstd * g[c0 + 2] + b[c0 + 2];
    o1.w = (a.w - mean) * rstd * g[c0 + 3] + b[c0 + 3];
    o2.x = (c.x - mean) * rstd * g[c0 + 4] + b[c0 + 4];
    o2.y = (c.y - mean) * rstd * g[c0 + 5] + b[c0 + 5];
    o2.z = (c.z - mean) * rstd * g[c0 + 6] + b[c0 + 6];
    o2.w = (c.w - mean) * rstd * g[c0 + 7] + b[c0 + 7];
    *(float4*)&out[(size_t)row * E + c0] = o1;
    *(float4*)&out[(size_t)row * E + c0 + 4] = o2;
}

extern "C" void kernel_launch(void* const* d_in, const int* in_sizes, int n_in,
                              void* d_out, int out_size, void* d_ws, size_t ws_size,
                              hipStream_t stream) {
    const float* emb = (const float*)d_in[0];
    const float* wq = (const float*)d_in[1];
    const float* bq = (const float*)d_in[2];
    const float* wk = (const float*)d_in[3];
    const float* bk = (const float*)d_in[4];
    const float* wv = (const float*)d_in[5];
    const float* bv = (const float*)d_in[6];
    const float* wo = (const float*)d_in[7];
    const float* bo = (const float*)d_in[8];
    const float* ln_g = (const float*)d_in[9];
    const float* ln_b = (const float*)d_in[10];
    float* out = (float*)d_out;

    char* ws = (char*)d_ws;
    // layout (bytes):
    //   embh   [8192*512 f16]  @ 0         (8 MB)
    //   wtqkv  [1536*512 f16]  @ 8388608   (1.5 MB)
    //   wto    [ 512*512 f16]  @ 9961472   (0.5 MB)
    //   Qb     [2*8*4096*64]   @ 10485760  (8 MB)   } reused as xbuf (fp32, 16MB)
    //   Kb     [2*8*4096*64]   @ 18874368  (8 MB)   } after attention
    //   Vt     [2*8*64*4096]   @ 27262976  (8 MB)
    //   attn   [8192*512 f16]  @ 35651584  (8 MB)
    f16* embh  = (f16*)(ws);
    f16* wtqkv = (f16*)(ws + 8388608);
    f16* wto   = (f16*)(ws + 9961472);
    f16* Qb    = (f16*)(ws + 10485760);
    f16* Kb    = (f16*)(ws + 18874368);
    f16* Vt    = (f16*)(ws + 27262976);
    f16* attnb = (f16*)(ws + 35651584);
    float* xbuf = (float*)(ws + 10485760);  // overlaps Qb+Kb (dead after attention)

    cvt_emb_kernel<<<dim3(2048), dim3(256), 0, stream>>>(emb, embh);
    cvt_w_kernel<<<dim3(2048), dim3(64), 0, stream>>>(wq, wk, wv, wo, wtqkv, wto);
    gemm_qkv_kernel<<<dim3(64, 12), dim3(256), 0, stream>>>(embh, wtqkv, bq, bk, bv, Qb, Kb, Vt);
    attn_kernel<<<dim3(64, 16), dim3(256), 0, stream>>>(Qb, Kb, Vt, attnb);
    gemm_out_kernel<<<dim3(64, 4), dim3(256), 0, stream>>>(attnb, wto, bo, emb, xbuf);
    ln_kernel<<<dim3(2048), dim3(256), 0, stream>>>(xbuf, ln_g, ln_b, out);
}

// Round 2
// 391.378 us; speedup vs baseline: 1.5717x; 1.5717x over previous
//
#include <hip/hip_runtime.h>

#define E 512
#define Hh 8
#define Dd 64
#define Ss 4096
#define Bb 2

typedef _Float16 f16;
typedef __attribute__((ext_vector_type(4))) _Float16 f16x4;
typedef __attribute__((ext_vector_type(8))) _Float16 f16x8;
typedef __attribute__((ext_vector_type(4))) float f32x4;

// ---------------- convert emb fp32 -> f16 ----------------
__global__ __launch_bounds__(256) void cvt_emb_kernel(const float* __restrict__ in,
                                                      f16* __restrict__ out) {
    int i = (blockIdx.x * 256 + threadIdx.x) * 8;
    float4 a = *(const float4*)(in + i);
    float4 b = *(const float4*)(in + i + 4);
    f16x8 o;
    o[0] = (f16)a.x; o[1] = (f16)a.y; o[2] = (f16)a.z; o[3] = (f16)a.w;
    o[4] = (f16)b.x; o[5] = (f16)b.y; o[6] = (f16)b.z; o[7] = (f16)b.w;
    *(f16x8*)(out + i) = o;
}

// ------------- transpose weights -> Wt[n][k] f16 -------------
__global__ __launch_bounds__(64) void cvt_w_kernel(const float* __restrict__ wq,
                                                   const float* __restrict__ wk,
                                                   const float* __restrict__ wv,
                                                   const float* __restrict__ wo,
                                                   f16* __restrict__ wtqkv,
                                                   f16* __restrict__ wto) {
    int n = blockIdx.x;      // 0..2047
    int t = threadIdx.x;     // 0..63
    const float* src;
    f16* dst;
    int col = n & 511;
    if (n < 1536) {
        int which = n >> 9;
        src = (which == 0) ? wq : (which == 1) ? wk : wv;
        dst = wtqkv + (size_t)n * E;
    } else {
        src = wo;
        dst = wto + (size_t)(n - 1536) * E;
    }
    int k0 = t * 8;
    f16x8 o;
#pragma unroll
    for (int j = 0; j < 8; ++j) o[j] = (f16)src[(size_t)(k0 + j) * E + col];
    *(f16x8*)(dst + k0) = o;
}

// ---------------- QKV projection GEMM ----------------
#define LDP 40

__global__ __launch_bounds__(256) void gemm_qkv_kernel(
    const f16* __restrict__ A, const f16* __restrict__ Wt,
    const float* __restrict__ bq, const float* __restrict__ bk,
    const float* __restrict__ bv,
    f16* __restrict__ Qb, f16* __restrict__ Kb, f16* __restrict__ Vt) {
    __shared__ f16 As[128 * LDP];
    __shared__ f16 Bs[128 * LDP];
    int tid = threadIdx.x;
    int m0 = blockIdx.x * 128, n0 = blockIdx.y * 128;
    int w = tid >> 6, lane = tid & 63;
    int wr = w >> 1, wc = w & 1;
    int lgrp = lane >> 4, l16 = lane & 15;
    f32x4 acc[4][4];
#pragma unroll
    for (int i = 0; i < 4; ++i)
#pragma unroll
        for (int j = 0; j < 4; ++j) acc[i][j] = (f32x4){0.f, 0.f, 0.f, 0.f};

    for (int kt = 0; kt < 16; ++kt) {
        int k0 = kt * 32;
        {
            int c = tid, row = c >> 2, seg = c & 3;
            *(f16x8*)&As[row * LDP + seg * 8] = *(const f16x8*)&A[(size_t)(m0 + row) * E + k0 + seg * 8];
            *(f16x8*)&Bs[row * LDP + seg * 8] = *(const f16x8*)&Wt[(size_t)(n0 + row) * E + k0 + seg * 8];
            c = tid + 256; row = c >> 2; seg = c & 3;
            *(f16x8*)&As[row * LDP + seg * 8] = *(const f16x8*)&A[(size_t)(m0 + row) * E + k0 + seg * 8];
            *(f16x8*)&Bs[row * LDP + seg * 8] = *(const f16x8*)&Wt[(size_t)(n0 + row) * E + k0 + seg * 8];
        }
        __syncthreads();
        f16x8 af[4], bfr[4];
#pragma unroll
        for (int mi = 0; mi < 4; ++mi)
            af[mi] = *(const f16x8*)&As[(wr * 64 + mi * 16 + l16) * LDP + lgrp * 8];
#pragma unroll
        for (int ni = 0; ni < 4; ++ni)
            bfr[ni] = *(const f16x8*)&Bs[(wc * 64 + ni * 16 + l16) * LDP + lgrp * 8];
#pragma unroll
        for (int mi = 0; mi < 4; ++mi)
#pragma unroll
            for (int ni = 0; ni < 4; ++ni)
                acc[mi][ni] = __builtin_amdgcn_mfma_f32_16x16x32_f16(af[mi], bfr[ni], acc[mi][ni], 0, 0, 0);
        __syncthreads();
    }
#pragma unroll
    for (int mi = 0; mi < 4; ++mi) {
#pragma unroll
        for (int ni = 0; ni < 4; ++ni) {
#pragma unroll
            for (int r = 0; r < 4; ++r) {
                int gm = m0 + wr * 64 + mi * 16 + lgrp * 4 + r;
                int gn = n0 + wc * 64 + ni * 16 + l16;
                int which = gn >> 9, e = gn & 511;
                int h = e >> 6, d = e & 63;
                int b = gm >> 12, s = gm & 4095;
                float v = acc[mi][ni][r];
                if (which == 0) {
                    // fold 1/sqrt(64) AND log2(e) into Q so attention works in exp2 domain
                    v = (v + bq[e]) * 0.180336880111f;
                    Qb[(size_t)((b * Hh + h) * Ss + s) * Dd + d] = (f16)v;
                } else if (which == 1) {
                    v += bk[e];
                    Kb[(size_t)((b * Hh + h) * Ss + s) * Dd + d] = (f16)v;
                } else {
                    v += bv[e];
                    Vt[(size_t)((b * Hh + h) * Dd + d) * Ss + s] = (f16)v;
                }
            }
        }
    }
}

// ---------------- causal flash attention (swapped QK^T) ----------------
// grid (32, B*H), block 256 = 4 waves. Wave handles q-tile = 127-(4*bx+w), QBLK=32, KVBLK=64.
// Swapped QK^T: mfma(K, Q) -> S^T; lane holds q = lane&15 (+16*nf), kv = 4*(lane>>4)+r (+16*mf).
// Softmax reduce over kv = in-lane 16 values + shfl_xor(16,32). P -> LDS [32][64] f16 with
// XOR swizzle (byte ^= (row&7)<<4) on both sides; PV reads P as A-frag, Vt as B-frag.
__global__ __launch_bounds__(256) void attn_kernel(const f16* __restrict__ Qb,
                                                   const f16* __restrict__ Kb,
                                                   const f16* __restrict__ Vt,
                                                   f16* __restrict__ attn) {
    __shared__ __align__(16) f16 Pl[4][32 * 64];
    __shared__ __align__(16) float SCL[4][32];
    int tid = threadIdx.x;
    int w = tid >> 6, lane = tid & 63;
    int g = lane >> 4, l16 = lane & 15;
    int bh = blockIdx.y;
    int tile = 127 - (blockIdx.x * 4 + w);   // heavy tiles dispatch first
    int q0 = tile * 32;
    const f16* Qp = Qb + (size_t)bh * Ss * Dd;
    const f16* Kp = Kb + (size_t)bh * Ss * Dd;
    const f16* Vp = Vt + (size_t)bh * Dd * Ss;
    f16* Pw = Pl[w];
    float* sclw = SCL[w];

    // Q fragments (B-operand): col = q = l16 (+16*nf), k = d = kc*32 + g*8 + j
    f16x8 qf[2][2];
#pragma unroll
    for (int nf = 0; nf < 2; ++nf)
#pragma unroll
        for (int kc = 0; kc < 2; ++kc)
            qf[nf][kc] = *(const f16x8*)&Qp[(size_t)(q0 + nf * 16 + l16) * Dd + kc * 32 + g * 8];

    f32x4 o[2][4];
#pragma unroll
    for (int mq = 0; mq < 2; ++mq)
#pragma unroll
        for (int nd = 0; nd < 4; ++nd) o[mq][nd] = (f32x4){0.f, 0.f, 0.f, 0.f};
    float m_run[2] = {-INFINITY, -INFINITY}, l_run[2] = {0.f, 0.f};

    int count = (tile >> 1) + 1;  // KV tiles of 64 covering kv <= q0+31
    for (int t = 0; t < count; ++t) {
        int n0 = t << 6;
        // K fragments (A-operand): row = kv = l16 (+16*mf), k = d
        f16x8 kf[4][2], vf[4][2];
#pragma unroll
        for (int mf = 0; mf < 4; ++mf)
#pragma unroll
            for (int kc = 0; kc < 2; ++kc)
                kf[mf][kc] = *(const f16x8*)&Kp[(size_t)(n0 + mf * 16 + l16) * Dd + kc * 32 + g * 8];
        // V fragments (B-operand for PV): col = d = l16 (+16*nd), k = kv contiguous
#pragma unroll
        for (int nd = 0; nd < 4; ++nd)
#pragma unroll
            for (int kc = 0; kc < 2; ++kc)
                vf[nd][kc] = *(const f16x8*)&Vp[(size_t)(nd * 16 + l16) * Ss + n0 + kc * 32 + g * 8];

        f32x4 s_[4][2];
#pragma unroll
        for (int mf = 0; mf < 4; ++mf)
#pragma unroll
            for (int nf = 0; nf < 2; ++nf) s_[mf][nf] = (f32x4){0.f, 0.f, 0.f, 0.f};
#pragma unroll
        for (int kc = 0; kc < 2; ++kc)
#pragma unroll
            for (int mf = 0; mf < 4; ++mf)
#pragma unroll
                for (int nf = 0; nf < 2; ++nf)
                    s_[mf][nf] = __builtin_amdgcn_mfma_f32_16x16x32_f16(kf[mf][kc], qf[nf][kc], s_[mf][nf], 0, 0, 0);

        if (t == count - 1) {  // only the last tile crosses the diagonal
#pragma unroll
            for (int mf = 0; mf < 4; ++mf)
#pragma unroll
                for (int nf = 0; nf < 2; ++nf)
#pragma unroll
                    for (int r = 0; r < 4; ++r) {
                        int kv = n0 + mf * 16 + 4 * g + r;
                        int qq = q0 + nf * 16 + l16;
                        if (kv > qq) s_[mf][nf][r] = -INFINITY;
                    }
        }

        float scl2[2];
#pragma unroll
        for (int nf = 0; nf < 2; ++nf) {
            float mx = -INFINITY;
#pragma unroll
            for (int mf = 0; mf < 4; ++mf)
#pragma unroll
                for (int r = 0; r < 4; ++r) mx = fmaxf(mx, s_[mf][nf][r]);
            mx = fmaxf(mx, __shfl_xor(mx, 16));
            mx = fmaxf(mx, __shfl_xor(mx, 32));
            float mn = fmaxf(m_run[nf], mx);
            float sc = exp2f(m_run[nf] - mn);
            float ss = 0.f;
#pragma unroll
            for (int mf = 0; mf < 4; ++mf)
#pragma unroll
                for (int r = 0; r < 4; ++r) {
                    float p = exp2f(s_[mf][nf][r] - mn);
                    s_[mf][nf][r] = p;
                    ss += p;
                }
            ss += __shfl_xor(ss, 16);
            ss += __shfl_xor(ss, 32);
            l_run[nf] = l_run[nf] * sc + ss;
            m_run[nf] = mn;
            scl2[nf] = sc;
        }

        // P -> LDS [row=q 32][col=kv 64] f16, XOR-swizzled (row stride 128B)
#pragma unroll
        for (int nf = 0; nf < 2; ++nf) {
            int row = nf * 16 + l16;
            char* base = (char*)Pw + row * 128;
            int swz = (row & 7) << 4;
#pragma unroll
            for (int mf = 0; mf < 4; ++mf) {
                f16x4 ph;
#pragma unroll
                for (int r = 0; r < 4; ++r) ph[r] = (f16)s_[mf][nf][r];
                *(f16x4*)(base + ((mf * 32 + g * 8) ^ swz)) = ph;
            }
        }
        if (lane < 16) { sclw[l16] = scl2[0]; sclw[16 + l16] = scl2[1]; }
        asm volatile("s_waitcnt lgkmcnt(0)" ::: "memory");
        __builtin_amdgcn_sched_barrier(0);

        // rescale O by per-q factor (broadcast via LDS, q = mq*16+4g+r)
        f32x4 sr[2];
#pragma unroll
        for (int mq = 0; mq < 2; ++mq) sr[mq] = *(const f32x4*)&sclw[mq * 16 + 4 * g];
#pragma unroll
        for (int mq = 0; mq < 2; ++mq)
#pragma unroll
            for (int nd = 0; nd < 4; ++nd)
#pragma unroll
                for (int r = 0; r < 4; ++r) o[mq][nd][r] *= sr[mq][r];

        // P A-frags: row = q = l16 (+16*mq), k = kv = kc*32+g*8+j (same swizzle)
        f16x8 pa[2][2];
#pragma unroll
        for (int mq = 0; mq < 2; ++mq) {
            int row = mq * 16 + l16;
            const char* base = (const char*)Pw + row * 128;
            int swz = (row & 7) << 4;
#pragma unroll
            for (int kc = 0; kc < 2; ++kc)
                pa[mq][kc] = *(const f16x8*)(base + ((kc * 64 + g * 16) ^ swz));
        }
#pragma unroll
        for (int kc = 0; kc < 2; ++kc)
#pragma unroll
            for (int mq = 0; mq < 2; ++mq)
#pragma unroll
                for (int nd = 0; nd < 4; ++nd)
                    o[mq][nd] = __builtin_amdgcn_mfma_f32_16x16x32_f16(pa[mq][kc], vf[nd][kc], o[mq][nd], 0, 0, 0);
    }

    // final 1/l, redistributed q->(g,r) via LDS
    if (lane < 16) { sclw[l16] = l_run[0]; sclw[16 + l16] = l_run[1]; }
    asm volatile("s_waitcnt lgkmcnt(0)" ::: "memory");
    __builtin_amdgcn_sched_barrier(0);
    int b = bh >> 3, h = bh & 7;
#pragma unroll
    for (int mq = 0; mq < 2; ++mq) {
        f32x4 lr = *(const f32x4*)&sclw[mq * 16 + 4 * g];
#pragma unroll
        for (int r = 0; r < 4; ++r) {
            float inv = 1.f / lr[r];
            int srow = q0 + mq * 16 + 4 * g + r;
#pragma unroll
            for (int nd = 0; nd < 4; ++nd)
                attn[(size_t)(b * Ss + srow) * E + h * 64 + nd * 16 + l16] = (f16)(o[mq][nd][r] * inv);
        }
    }
}

// ---------------- output projection + bias + residual ----------------
__global__ __launch_bounds__(256) void gemm_out_kernel(
    const f16* __restrict__ A, const f16* __restrict__ Wt,
    const float* __restrict__ bo, const float* __restrict__ emb,
    float* __restrict__ xout) {
    __shared__ f16 As[128 * LDP];
    __shared__ f16 Bs[128 * LDP];
    int tid = threadIdx.x;
    int m0 = blockIdx.x * 128, n0 = blockIdx.y * 128;
    int w = tid >> 6, lane = tid & 63;
    int wr = w >> 1, wc = w & 1;
    int lgrp = lane >> 4, l16 = lane & 15;
    f32x4 acc[4][4];
#pragma unroll
    for (int i = 0; i < 4; ++i)
#pragma unroll
        for (int j = 0; j < 4; ++j) acc[i][j] = (f32x4){0.f, 0.f, 0.f, 0.f};

    for (int kt = 0; kt < 16; ++kt) {
        int k0 = kt * 32;
        {
            int c = tid, row = c >> 2, seg = c & 3;
            *(f16x8*)&As[row * LDP + seg * 8] = *(const f16x8*)&A[(size_t)(m0 + row) * E + k0 + seg * 8];
            *(f16x8*)&Bs[row * LDP + seg * 8] = *(const f16x8*)&Wt[(size_t)(n0 + row) * E + k0 + seg * 8];
            c = tid + 256; row = c >> 2; seg = c & 3;
            *(f16x8*)&As[row * LDP + seg * 8] = *(const f16x8*)&A[(size_t)(m0 + row) * E + k0 + seg * 8];
            *(f16x8*)&Bs[row * LDP + seg * 8] = *(const f16x8*)&Wt[(size_t)(n0 + row) * E + k0 + seg * 8];
        }
        __syncthreads();
        f16x8 af[4], bfr[4];
#pragma unroll
        for (int mi = 0; mi < 4; ++mi)
            af[mi] = *(const f16x8*)&As[(wr * 64 + mi * 16 + l16) * LDP + lgrp * 8];
#pragma unroll
        for (int ni = 0; ni < 4; ++ni)
            bfr[ni] = *(const f16x8*)&Bs[(wc * 64 + ni * 16 + l16) * LDP + lgrp * 8];
#pragma unroll
        for (int mi = 0; mi < 4; ++mi)
#pragma unroll
            for (int ni = 0; ni < 4; ++ni)
                acc[mi][ni] = __builtin_amdgcn_mfma_f32_16x16x32_f16(af[mi], bfr[ni], acc[mi][ni], 0, 0, 0);
        __syncthreads();
    }
#pragma unroll
    for (int mi = 0; mi < 4; ++mi) {
#pragma unroll
        for (int ni = 0; ni < 4; ++ni) {
#pragma unroll
            for (int r = 0; r < 4; ++r) {
                int gm = m0 + wr * 64 + mi * 16 + lgrp * 4 + r;
                int gn = n0 + wc * 64 + ni * 16 + l16;
                size_t idx = (size_t)gm * E + gn;
                xout[idx] = acc[mi][ni][r] + bo[gn] + emb[idx];
            }
        }
    }
}

// ---------------- LayerNorm ----------------
__global__ __launch_bounds__(256) void ln_kernel(const float* __restrict__ x,
                                                 const float* __restrict__ g,
                                                 const float* __restrict__ b,
                                                 float* __restrict__ out) {
    int w = threadIdx.x >> 6, lane = threadIdx.x & 63;
    int row = blockIdx.x * 4 + w;
    const float* xr = x + (size_t)row * E;
    int c0 = lane * 8;
    float4 a = *(const float4*)&xr[c0];
    float4 c = *(const float4*)&xr[c0 + 4];
    float s = a.x + a.y + a.z + a.w + c.x + c.y + c.z + c.w;
    float q = a.x * a.x + a.y * a.y + a.z * a.z + a.w * a.w +
              c.x * c.x + c.y * c.y + c.z * c.z + c.w * c.w;
#pragma unroll
    for (int m = 1; m <= 32; m <<= 1) {
        s += __shfl_xor(s, m);
        q += __shfl_xor(q, m);
    }
    float mean = s * (1.f / 512.f);
    float var = q * (1.f / 512.f) - mean * mean;
    float rstd = rsqrtf(var + 1e-5f);
    float4 o1, o2;
    o1.x = (a.x - mean) * rstd * g[c0 + 0] + b[c0 + 0];
    o1.y = (a.y - mean) * rstd * g[c0 + 1] + b[c0 + 1];
    o1.z = (a.z - mean) * rstd * g[c0 + 2] + b[c0 + 2];
    o1.w = (a.w - mean) * rstd * g[c0 + 3] + b[c0 + 3];
    o2.x = (c.x - mean) * rstd * g[c0 + 4] + b[c0 + 4];
    o2.y = (c.y - mean) * rstd * g[c0 + 5] + b[c0 + 5];
    o2.z = (c.z - mean) * rstd * g[c0 + 6] + b[c0 + 6];
    o2.w = (c.w - mean) * rstd * g[c0 + 7] + b[c0 + 7];
    *(float4*)&out[(size_t)row * E + c0] = o1;
    *(float4*)&out[(size_t)row * E + c0 + 4] = o2;
}

extern "C" void kernel_launch(void* const* d_in, const int* in_sizes, int n_in,
                              void* d_out, int out_size, void* d_ws, size_t ws_size,
                              hipStream_t stream) {
    const float* emb = (const float*)d_in[0];
    const float* wq = (const float*)d_in[1];
    const float* bq = (const float*)d_in[2];
    const float* wk = (const float*)d_in[3];
    const float* bk = (const float*)d_in[4];
    const float* wv = (const float*)d_in[5];
    const float* bv = (const float*)d_in[6];
    const float* wo = (const float*)d_in[7];
    const float* bo = (const float*)d_in[8];
    const float* ln_g = (const float*)d_in[9];
    const float* ln_b = (const float*)d_in[10];
    float* out = (float*)d_out;

    char* ws = (char*)d_ws;
    f16* embh  = (f16*)(ws);
    f16* wtqkv = (f16*)(ws + 8388608);
    f16* wto   = (f16*)(ws + 9961472);
    f16* Qb    = (f16*)(ws + 10485760);
    f16* Kb    = (f16*)(ws + 18874368);
    f16* Vt    = (f16*)(ws + 27262976);
    f16* attnb = (f16*)(ws + 35651584);
    float* xbuf = (float*)(ws + 10485760);  // overlaps Qb+Kb (dead after attention)

    cvt_emb_kernel<<<dim3(2048), dim3(256), 0, stream>>>(emb, embh);
    cvt_w_kernel<<<dim3(2048), dim3(64), 0, stream>>>(wq, wk, wv, wo, wtqkv, wto);
    gemm_qkv_kernel<<<dim3(64, 12), dim3(256), 0, stream>>>(embh, wtqkv, bq, bk, bv, Qb, Kb, Vt);
    attn_kernel<<<dim3(32, 16), dim3(256), 0, stream>>>(Qb, Kb, Vt, attnb);
    gemm_out_kernel<<<dim3(64, 4), dim3(256), 0, stream>>>(attnb, wto, bo, emb, xbuf);
    ln_kernel<<<dim3(2048), dim3(256), 0, stream>>>(xbuf, ln_g, ln_b, out);
}